// Round 3
// baseline (1490.352 us; speedup 1.0000x reference)
//
#include <hip/hip_runtime.h>

typedef _Float16 half8 __attribute__((ext_vector_type(8)));
typedef float f32x4 __attribute__((ext_vector_type(4)));

namespace {

constexpr int HEADS = 8;
constexpr int BATCH = 512;
constexpr int DH    = 1024;          // per-head dim
constexpr int CHW   = HEADS * DH;    // 8192

constexpr int BM = 128, BN = 128, BK = 32;
constexpr int LDW = BK + 8;          // padded LDS stride (halves): 40

// dispatch-index d runs on XCD d%8; give each XCD a contiguous logical chunk
__device__ __forceinline__ int xcd_swz(int bid, int nwg) {
  const int q = nwg >> 3;  // all our grids are %8 == 0
  return (bid & 7) * q + (bid >> 3);
}

__device__ __forceinline__ void cvt16(const float* f, half8& h0, half8& h1) {
#pragma unroll
  for (int i = 0; i < 8; ++i) { h0[i] = (_Float16)f[i]; h1[i] = (_Float16)f[8 + i]; }
}

// Fused Q/K/V projection. z selects (X, W, bias, dst).
// P[n,h,e] = sum_d X[n,h,d]*W[h,e,d] + b[h,e]; V written transposed [h][e][n].
// Double-buffered LDS, ONE barrier per K-step, 1-ahead register prefetch.
__global__ __launch_bounds__(256, 4) void proj_kernel(
    const float* __restrict__ Xq, const float* __restrict__ Xk, const float* __restrict__ Xv,
    const float* __restrict__ W1, const float* __restrict__ b1,
    const float* __restrict__ W2, const float* __restrict__ b2,
    const float* __restrict__ W3, const float* __restrict__ b3,
    _Float16* __restrict__ Qp, _Float16* __restrict__ Kp, _Float16* __restrict__ VpT) {
  __shared__ _Float16 As[2][BM * LDW];
  __shared__ _Float16 Bs[2][BN * LDW];
  const int tid = threadIdx.x;
  const int l  = xcd_swz(blockIdx.x, 768);
  const int z  = l >> 8, rem = l & 255;
  const int h  = rem >> 5, bx = rem & 31;
  const int tm = bx & 3, tn = bx >> 2;
  const float* X    = (z == 0) ? Xq : (z == 1) ? Xk : Xv;
  const float* W    = (z == 0) ? W1 : (z == 1) ? W2 : W3;
  const float* bias = (z == 0) ? b1 : (z == 1) ? b2 : b3;
  _Float16*    P    = (z == 0) ? Qp : (z == 1) ? Kp : VpT;

  const int lane = tid & 63, w = tid >> 6;
  const int wr = (w >> 1) * 64, wc = (w & 1) * 64;
  const int lr = lane & 15, lk = lane >> 4;
  const int srow = tid >> 1, sc0 = (tid & 1) * 16;

  const float* ga = X + (size_t)(tm * BM + srow) * CHW + (size_t)h * DH + sc0;
  const float* gb = W + (size_t)h * DH * DH + (size_t)(tn * BN + srow) * DH + sc0;

  constexpr int NT = DH / BK;  // 32
  float4 ra[4], rb[4];
  // prologue: tile0 -> regs -> cvt -> buf0; tile1 -> regs
#pragma unroll
  for (int i = 0; i < 4; ++i) { ra[i] = ((const float4*)ga)[i]; rb[i] = ((const float4*)gb)[i]; }
  ga += BK; gb += BK;
  {
    half8 a0, a1, b0, b1;
    cvt16((const float*)ra, a0, a1);
    cvt16((const float*)rb, b0, b1);
    *(half8*)&As[0][srow * LDW + sc0]     = a0;
    *(half8*)&As[0][srow * LDW + sc0 + 8] = a1;
    *(half8*)&Bs[0][srow * LDW + sc0]     = b0;
    *(half8*)&Bs[0][srow * LDW + sc0 + 8] = b1;
  }
#pragma unroll
  for (int i = 0; i < 4; ++i) { ra[i] = ((const float4*)ga)[i]; rb[i] = ((const float4*)gb)[i]; }
  ga += BK; gb += BK;
  __syncthreads();

  f32x4 acc[4][4] = {};
  int c = 0;
#pragma unroll 1
  for (int t = 0; t < NT; ++t) {
    const _Float16* Ac = As[c];
    const _Float16* Bc = Bs[c];
    // fragments of current tile
    half8 av[4], bv[4];
#pragma unroll
    for (int i = 0; i < 4; ++i)
      av[i] = *(const half8*)&Ac[(wr + i * 16 + lr) * LDW + lk * 8];
#pragma unroll
    for (int j = 0; j < 4; ++j)
      bv[j] = *(const half8*)&Bc[(wc + j * 16 + lr) * LDW + lk * 8];
    // stage tile t+1 into the other buffer; prefetch tile t+2 into regs
    if (t + 1 < NT) {
      _Float16* An = As[c ^ 1];
      _Float16* Bn = Bs[c ^ 1];
      half8 a0, a1, b0, b1;
      cvt16((const float*)ra, a0, a1);
      cvt16((const float*)rb, b0, b1);
      *(half8*)&An[srow * LDW + sc0]     = a0;
      *(half8*)&An[srow * LDW + sc0 + 8] = a1;
      *(half8*)&Bn[srow * LDW + sc0]     = b0;
      *(half8*)&Bn[srow * LDW + sc0 + 8] = b1;
      if (t + 2 < NT) {
#pragma unroll
        for (int i = 0; i < 4; ++i) { ra[i] = ((const float4*)ga)[i]; rb[i] = ((const float4*)gb)[i]; }
        ga += BK; gb += BK;
      }
    }
#pragma unroll
    for (int i = 0; i < 4; ++i)
#pragma unroll
      for (int j = 0; j < 4; ++j)
        acc[i][j] = __builtin_amdgcn_mfma_f32_16x16x32_f16(av[i], bv[j], acc[i][j], 0, 0, 0);
    __syncthreads();
    c ^= 1;
  }

#pragma unroll
  for (int i = 0; i < 4; ++i)
#pragma unroll
    for (int j = 0; j < 4; ++j) {
      const int e = tn * BN + wc + j * 16 + lr;
      const float bb = bias[h * DH + e];
#pragma unroll
      for (int q = 0; q < 4; ++q) {
        const int n = tm * BM + wr + i * 16 + lk * 4 + q;
        const float val = acc[i][j][q] + bb;
        if (z != 2) P[((size_t)n * HEADS + h) * DH + e] = (_Float16)val;
        else        P[((size_t)h * DH + e) * BATCH + n] = (_Float16)val;
      }
    }
}

// Generic f16 NT-GEMM body: dbuf LDS, one barrier/iter, 2-ahead reg prefetch.
// A rows stride sA, B rows stride sB, NT K-steps. Result in acc.
template <int NT>
__device__ __forceinline__ void gemm_f16_core(
    const _Float16* ga, const _Float16* gb, size_t sA, size_t sB,
    _Float16 (*As)[BM * LDW], _Float16 (*Bs)[BN * LDW],
    int srow, int sc0, int wr, int wc, int lr, int lk, f32x4 (&acc)[4][4]) {
  half8 rA[2][2], rB[2][2];
  // prologue: tile0 -> R0, tile1 -> R1; write tile0; barrier
  rA[0][0] = ((const half8*)ga)[0]; rA[0][1] = ((const half8*)ga)[1];
  rB[0][0] = ((const half8*)gb)[0]; rB[0][1] = ((const half8*)gb)[1];
  ga += BK; gb += BK;
  rA[1][0] = ((const half8*)ga)[0]; rA[1][1] = ((const half8*)ga)[1];
  rB[1][0] = ((const half8*)gb)[0]; rB[1][1] = ((const half8*)gb)[1];
  ga += BK; gb += BK;
  *(half8*)&As[0][srow * LDW + sc0]     = rA[0][0];
  *(half8*)&As[0][srow * LDW + sc0 + 8] = rA[0][1];
  *(half8*)&Bs[0][srow * LDW + sc0]     = rB[0][0];
  *(half8*)&Bs[0][srow * LDW + sc0 + 8] = rB[0][1];
  __syncthreads();

  int c = 0;
#pragma unroll 1
  for (int t = 0; t < NT; ++t) {
    const _Float16* Ac = As[c];
    const _Float16* Bc = Bs[c];
    half8 av[4], bv[4];
#pragma unroll
    for (int i = 0; i < 4; ++i)
      av[i] = *(const half8*)&Ac[(wr + i * 16 + lr) * LDW + lk * 8];
#pragma unroll
    for (int j = 0; j < 4; ++j)
      bv[j] = *(const half8*)&Bc[(wc + j * 16 + lr) * LDW + lk * 8];
    if (t + 2 < NT) {  // issue loads for tile t+2 into the reg slot freed last iter
      rA[t & 1][0] = ((const half8*)ga)[0]; rA[t & 1][1] = ((const half8*)ga)[1];
      rB[t & 1][0] = ((const half8*)gb)[0]; rB[t & 1][1] = ((const half8*)gb)[1];
      ga += BK; gb += BK;
    }
    if (t + 1 < NT) {  // write tile t+1 (loaded two iters ago) into other buffer
      _Float16* An = As[c ^ 1];
      _Float16* Bn = Bs[c ^ 1];
      *(half8*)&An[srow * LDW + sc0]     = rA[(t + 1) & 1][0];
      *(half8*)&An[srow * LDW + sc0 + 8] = rA[(t + 1) & 1][1];
      *(half8*)&Bn[srow * LDW + sc0]     = rB[(t + 1) & 1][0];
      *(half8*)&Bn[srow * LDW + sc0 + 8] = rB[(t + 1) & 1][1];
    }
#pragma unroll
    for (int i = 0; i < 4; ++i)
#pragma unroll
      for (int j = 0; j < 4; ++j)
        acc[i][j] = __builtin_amdgcn_mfma_f32_16x16x32_f16(av[i], bv[j], acc[i][j], 0, 0, 0);
    __syncthreads();
    c ^= 1;
  }
}

// S[h,n,m] = 32 * sum_e Qp[n,h,e] * Kp[m,h,e]   (fp32 out)
__global__ __launch_bounds__(256, 4) void score_kernel(
    const _Float16* __restrict__ Qp, const _Float16* __restrict__ Kp,
    float* __restrict__ S) {
  __shared__ _Float16 As[2][BM * LDW];
  __shared__ _Float16 Bs[2][BN * LDW];
  const int tid = threadIdx.x;
  const int l  = xcd_swz(blockIdx.x, 128);
  const int h  = l >> 4, bx = l & 15;
  const int tm = bx & 3, tn = bx >> 2;
  const int lane = tid & 63, w = tid >> 6;
  const int wr = (w >> 1) * 64, wc = (w & 1) * 64;
  const int lr = lane & 15, lk = lane >> 4;
  const int srow = tid >> 1, sc0 = (tid & 1) * 16;

  const _Float16* ga = Qp + ((size_t)(tm * BM + srow) * HEADS + h) * DH + sc0;
  const _Float16* gb = Kp + ((size_t)(tn * BN + srow) * HEADS + h) * DH + sc0;

  f32x4 acc[4][4] = {};
  gemm_f16_core<DH / BK>(ga, gb, CHW, CHW, As, Bs, srow, sc0, wr, wc, lr, lk, acc);

#pragma unroll
  for (int i = 0; i < 4; ++i)
#pragma unroll
    for (int j = 0; j < 4; ++j) {
      const int m = tn * BN + wc + j * 16 + lr;
#pragma unroll
      for (int q = 0; q < 4; ++q) {
        const int n = tm * BM + wr + i * 16 + lk * 4 + q;
        S[((size_t)h * BATCH + n) * BATCH + m] = 32.0f * acc[i][j][q];
      }
    }
}

// row-softmax over m (512), one wave per (h,n) row; fp32 in, fp16 out
__global__ __launch_bounds__(64) void softmax_kernel(
    const float* __restrict__ S, _Float16* __restrict__ A) {
  const size_t r = (size_t)blockIdx.x * BATCH;
  const int l = threadIdx.x;
  float v[8];
  float mx = -1e30f;
#pragma unroll
  for (int i = 0; i < 8; ++i) { v[i] = S[r + i * 64 + l]; mx = fmaxf(mx, v[i]); }
#pragma unroll
  for (int off = 32; off; off >>= 1) mx = fmaxf(mx, __shfl_xor(mx, off));
  float sum = 0.f;
#pragma unroll
  for (int i = 0; i < 8; ++i) { v[i] = __expf(v[i] - mx); sum += v[i]; }
#pragma unroll
  for (int off = 32; off; off >>= 1) sum += __shfl_xor(sum, off);
  const float inv = 1.f / sum;
#pragma unroll
  for (int i = 0; i < 8; ++i) A[r + i * 64 + l] = (_Float16)(v[i] * inv);
}

// Out[n,h,e] = sum_m At[h,n,m] * VpT[h,e,m]   (fp32 out)
__global__ __launch_bounds__(256, 4) void pv_kernel(
    const _Float16* __restrict__ At, const _Float16* __restrict__ VpT,
    float* __restrict__ Out) {
  __shared__ _Float16 As[2][BM * LDW];
  __shared__ _Float16 Bs[2][BN * LDW];
  const int tid = threadIdx.x;
  const int l  = xcd_swz(blockIdx.x, 256);
  const int h  = l >> 5, bx = l & 31;
  const int tm = bx & 3, tn = bx >> 2;
  const int lane = tid & 63, w = tid >> 6;
  const int wr = (w >> 1) * 64, wc = (w & 1) * 64;
  const int lr = lane & 15, lk = lane >> 4;
  const int srow = tid >> 1, sc0 = (tid & 1) * 16;

  const _Float16* ga = At  + ((size_t)h * BATCH + tm * BM + srow) * BATCH + sc0;
  const _Float16* gb = VpT + ((size_t)h * DH   + tn * BN + srow) * BATCH + sc0;

  f32x4 acc[4][4] = {};
  gemm_f16_core<BATCH / BK>(ga, gb, BATCH, BATCH, As, Bs, srow, sc0, wr, wc, lr, lk, acc);

#pragma unroll
  for (int i = 0; i < 4; ++i)
#pragma unroll
    for (int j = 0; j < 4; ++j) {
      const int e = tn * BN + wc + j * 16 + lr;
#pragma unroll
      for (int q = 0; q < 4; ++q) {
        const int n = tm * BM + wr + i * 16 + lk * 4 + q;
        Out[((size_t)n * HEADS + h) * DH + e] = acc[i][j][q];
      }
    }
}

}  // namespace

extern "C" void kernel_launch(void* const* d_in, const int* in_sizes, int n_in,
                              void* d_out, int out_size, void* d_ws, size_t ws_size,
                              hipStream_t stream) {
  (void)in_sizes; (void)n_in; (void)out_size; (void)ws_size;
  const float* q  = (const float*)d_in[0];
  const float* k  = (const float*)d_in[1];
  const float* v  = (const float*)d_in[2];
  const float* W1 = (const float*)d_in[3];
  const float* b1 = (const float*)d_in[4];
  const float* W2 = (const float*)d_in[5];
  const float* b2 = (const float*)d_in[6];
  const float* W3 = (const float*)d_in[7];
  const float* b3 = (const float*)d_in[8];
  float* out = (float*)d_out;

  // workspace layout (36 MB total)
  _Float16* Qp  = (_Float16*)d_ws;                       // 8 MB
  _Float16* Kp  = Qp + (size_t)BATCH * HEADS * DH;       // 8 MB
  _Float16* VpT = Kp + (size_t)BATCH * HEADS * DH;       // 8 MB ([h][e][m])
  float*    S   = (float*)(VpT + (size_t)BATCH * HEADS * DH);      // 8 MB
  _Float16* At  = (_Float16*)(S + (size_t)HEADS * BATCH * BATCH);  // 4 MB

  const dim3 blk(256);
  proj_kernel<<<dim3(768), blk, 0, stream>>>(q, k, v, W1, b1, W2, b2, W3, b3, Qp, Kp, VpT);
  score_kernel<<<dim3(128), blk, 0, stream>>>(Qp, Kp, S);
  softmax_kernel<<<dim3(HEADS * BATCH), dim3(64), 0, stream>>>(S, At);
  pv_kernel<<<dim3(256), blk, 0, stream>>>(At, VpT, out);
}

// Round 4
// 434.767 us; speedup vs baseline: 3.4279x; 3.4279x over previous
//
#include <hip/hip_runtime.h>

typedef _Float16 half8 __attribute__((ext_vector_type(8)));
typedef float f32x4 __attribute__((ext_vector_type(4)));

namespace {

constexpr int HEADS = 8;
constexpr int BATCH = 512;
constexpr int DH    = 1024;          // per-head dim
constexpr int CHW   = HEADS * DH;    // 8192

constexpr int BM = 128, BN = 128, BK = 32;
constexpr int LDW = BK + 8;          // padded LDS stride (halves): 40

// dispatch-index d runs on XCD d%8; give each XCD a contiguous logical chunk
__device__ __forceinline__ int xcd_swz(int bid, int nwg) {
  const int q = nwg >> 3;  // all our grids are %8 == 0
  return (bid & 7) * q + (bid >> 3);
}

__device__ __forceinline__ void cvt16(const float* f, half8& h0, half8& h1) {
#pragma unroll
  for (int i = 0; i < 8; ++i) { h0[i] = (_Float16)f[i]; h1[i] = (_Float16)f[8 + i]; }
}

// Fused Q/K/V projection. z selects (X, W, bias, dst).
// P[n,h,e] = sum_d X[n,h,d]*W[h,e,d] + b[h,e]; V written transposed [h][e][n].
// Double-buffered LDS, ONE barrier per K-step, 1-ahead register prefetch (static regs).
__global__ __launch_bounds__(256, 4) void proj_kernel(
    const float* __restrict__ Xq, const float* __restrict__ Xk, const float* __restrict__ Xv,
    const float* __restrict__ W1, const float* __restrict__ b1,
    const float* __restrict__ W2, const float* __restrict__ b2,
    const float* __restrict__ W3, const float* __restrict__ b3,
    _Float16* __restrict__ Qp, _Float16* __restrict__ Kp, _Float16* __restrict__ VpT) {
  __shared__ _Float16 As[2][BM * LDW];
  __shared__ _Float16 Bs[2][BN * LDW];
  const int tid = threadIdx.x;
  const int l  = xcd_swz(blockIdx.x, 768);
  const int z  = l >> 8, rem = l & 255;
  const int h  = rem >> 5, bx = rem & 31;
  const int tm = bx & 3, tn = bx >> 2;
  const float* X    = (z == 0) ? Xq : (z == 1) ? Xk : Xv;
  const float* W    = (z == 0) ? W1 : (z == 1) ? W2 : W3;
  const float* bias = (z == 0) ? b1 : (z == 1) ? b2 : b3;
  _Float16*    P    = (z == 0) ? Qp : (z == 1) ? Kp : VpT;

  const int lane = tid & 63, w = tid >> 6;
  const int wr = (w >> 1) * 64, wc = (w & 1) * 64;
  const int lr = lane & 15, lk = lane >> 4;
  const int srow = tid >> 1, sc0 = (tid & 1) * 16;

  const float* ga = X + (size_t)(tm * BM + srow) * CHW + (size_t)h * DH + sc0;
  const float* gb = W + (size_t)h * DH * DH + (size_t)(tn * BN + srow) * DH + sc0;

  constexpr int NT = DH / BK;  // 32
  float4 ra0, ra1, ra2, ra3, rb0, rb1, rb2, rb3;
  // prologue: tile0 -> regs -> cvt -> buf0; tile1 -> regs
  ra0 = ((const float4*)ga)[0]; ra1 = ((const float4*)ga)[1];
  ra2 = ((const float4*)ga)[2]; ra3 = ((const float4*)ga)[3];
  rb0 = ((const float4*)gb)[0]; rb1 = ((const float4*)gb)[1];
  rb2 = ((const float4*)gb)[2]; rb3 = ((const float4*)gb)[3];
  ga += BK; gb += BK;
  {
    float fa[16], fb[16];
    *(float4*)&fa[0] = ra0; *(float4*)&fa[4] = ra1; *(float4*)&fa[8] = ra2; *(float4*)&fa[12] = ra3;
    *(float4*)&fb[0] = rb0; *(float4*)&fb[4] = rb1; *(float4*)&fb[8] = rb2; *(float4*)&fb[12] = rb3;
    half8 a0, a1, b0, b1;
    cvt16(fa, a0, a1);
    cvt16(fb, b0, b1);
    *(half8*)&As[0][srow * LDW + sc0]     = a0;
    *(half8*)&As[0][srow * LDW + sc0 + 8] = a1;
    *(half8*)&Bs[0][srow * LDW + sc0]     = b0;
    *(half8*)&Bs[0][srow * LDW + sc0 + 8] = b1;
  }
  ra0 = ((const float4*)ga)[0]; ra1 = ((const float4*)ga)[1];
  ra2 = ((const float4*)ga)[2]; ra3 = ((const float4*)ga)[3];
  rb0 = ((const float4*)gb)[0]; rb1 = ((const float4*)gb)[1];
  rb2 = ((const float4*)gb)[2]; rb3 = ((const float4*)gb)[3];
  ga += BK; gb += BK;
  __syncthreads();

  f32x4 acc[4][4] = {};
  int c = 0;
#pragma unroll 1
  for (int t = 0; t < NT; ++t) {
    const _Float16* Ac = As[c];
    const _Float16* Bc = Bs[c];
    half8 av[4], bv[4];
#pragma unroll
    for (int i = 0; i < 4; ++i)
      av[i] = *(const half8*)&Ac[(wr + i * 16 + lr) * LDW + lk * 8];
#pragma unroll
    for (int j = 0; j < 4; ++j)
      bv[j] = *(const half8*)&Bc[(wc + j * 16 + lr) * LDW + lk * 8];
    if (t + 1 < NT) {  // stage tile t+1 (in regs) into other buffer
      float fa[16], fb[16];
      *(float4*)&fa[0] = ra0; *(float4*)&fa[4] = ra1; *(float4*)&fa[8] = ra2; *(float4*)&fa[12] = ra3;
      *(float4*)&fb[0] = rb0; *(float4*)&fb[4] = rb1; *(float4*)&fb[8] = rb2; *(float4*)&fb[12] = rb3;
      half8 a0, a1, b0, b1;
      cvt16(fa, a0, a1);
      cvt16(fb, b0, b1);
      _Float16* An = As[c ^ 1];
      _Float16* Bn = Bs[c ^ 1];
      *(half8*)&An[srow * LDW + sc0]     = a0;
      *(half8*)&An[srow * LDW + sc0 + 8] = a1;
      *(half8*)&Bn[srow * LDW + sc0]     = b0;
      *(half8*)&Bn[srow * LDW + sc0 + 8] = b1;
      if (t + 2 < NT) {  // prefetch tile t+2 into (now free) named regs
        ra0 = ((const float4*)ga)[0]; ra1 = ((const float4*)ga)[1];
        ra2 = ((const float4*)ga)[2]; ra3 = ((const float4*)ga)[3];
        rb0 = ((const float4*)gb)[0]; rb1 = ((const float4*)gb)[1];
        rb2 = ((const float4*)gb)[2]; rb3 = ((const float4*)gb)[3];
        ga += BK; gb += BK;
      }
    }
#pragma unroll
    for (int i = 0; i < 4; ++i)
#pragma unroll
      for (int j = 0; j < 4; ++j)
        acc[i][j] = __builtin_amdgcn_mfma_f32_16x16x32_f16(av[i], bv[j], acc[i][j], 0, 0, 0);
    __syncthreads();
    c ^= 1;
  }

#pragma unroll
  for (int i = 0; i < 4; ++i)
#pragma unroll
    for (int j = 0; j < 4; ++j) {
      const int e = tn * BN + wc + j * 16 + lr;
      const float bb = bias[h * DH + e];
#pragma unroll
      for (int q = 0; q < 4; ++q) {
        const int n = tm * BM + wr + i * 16 + lk * 4 + q;
        const float val = acc[i][j][q] + bb;
        if (z != 2) P[((size_t)n * HEADS + h) * DH + e] = (_Float16)val;
        else        P[((size_t)h * DH + e) * BATCH + n] = (_Float16)val;
      }
    }
}

// f16 NT-GEMM body: dbuf LDS, one barrier/iter, single STATIC prefetch slot.
// (rule #20: never index staging regs with a runtime value)
template <int NT>
__device__ __forceinline__ void gemm_f16_core(
    const _Float16* ga, const _Float16* gb,
    _Float16 (*As)[BM * LDW], _Float16 (*Bs)[BN * LDW],
    int srow, int sc0, int wr, int wc, int lr, int lk, f32x4 (&acc)[4][4]) {
  // tile0 -> regs -> buf0
  half8 rA0 = ((const half8*)ga)[0], rA1 = ((const half8*)ga)[1];
  half8 rB0 = ((const half8*)gb)[0], rB1 = ((const half8*)gb)[1];
  ga += BK; gb += BK;
  *(half8*)&As[0][srow * LDW + sc0]     = rA0;
  *(half8*)&As[0][srow * LDW + sc0 + 8] = rA1;
  *(half8*)&Bs[0][srow * LDW + sc0]     = rB0;
  *(half8*)&Bs[0][srow * LDW + sc0 + 8] = rB1;
  // tile1 -> regs
  rA0 = ((const half8*)ga)[0]; rA1 = ((const half8*)ga)[1];
  rB0 = ((const half8*)gb)[0]; rB1 = ((const half8*)gb)[1];
  ga += BK; gb += BK;
  __syncthreads();

  int c = 0;
#pragma unroll 1
  for (int t = 0; t < NT; ++t) {
    const _Float16* Ac = As[c];
    const _Float16* Bc = Bs[c];
    half8 av[4], bv[4];
#pragma unroll
    for (int i = 0; i < 4; ++i)
      av[i] = *(const half8*)&Ac[(wr + i * 16 + lr) * LDW + lk * 8];
#pragma unroll
    for (int j = 0; j < 4; ++j)
      bv[j] = *(const half8*)&Bc[(wc + j * 16 + lr) * LDW + lk * 8];
    if (t + 1 < NT) {  // write tile t+1 (held in regs) into other buffer
      _Float16* An = As[c ^ 1];
      _Float16* Bn = Bs[c ^ 1];
      *(half8*)&An[srow * LDW + sc0]     = rA0;
      *(half8*)&An[srow * LDW + sc0 + 8] = rA1;
      *(half8*)&Bn[srow * LDW + sc0]     = rB0;
      *(half8*)&Bn[srow * LDW + sc0 + 8] = rB1;
      if (t + 2 < NT) {  // issue loads for tile t+2 into the same named regs
        rA0 = ((const half8*)ga)[0]; rA1 = ((const half8*)ga)[1];
        rB0 = ((const half8*)gb)[0]; rB1 = ((const half8*)gb)[1];
        ga += BK; gb += BK;
      }
    }
#pragma unroll
    for (int i = 0; i < 4; ++i)
#pragma unroll
      for (int j = 0; j < 4; ++j)
        acc[i][j] = __builtin_amdgcn_mfma_f32_16x16x32_f16(av[i], bv[j], acc[i][j], 0, 0, 0);
    __syncthreads();
    c ^= 1;
  }
}

// S[h,n,m] = 32 * sum_e Qp[n,h,e] * Kp[m,h,e]   (fp32 out)
__global__ __launch_bounds__(256, 4) void score_kernel(
    const _Float16* __restrict__ Qp, const _Float16* __restrict__ Kp,
    float* __restrict__ S) {
  __shared__ _Float16 As[2][BM * LDW];
  __shared__ _Float16 Bs[2][BN * LDW];
  const int tid = threadIdx.x;
  const int l  = xcd_swz(blockIdx.x, 128);
  const int h  = l >> 4, bx = l & 15;
  const int tm = bx & 3, tn = bx >> 2;
  const int lane = tid & 63, w = tid >> 6;
  const int wr = (w >> 1) * 64, wc = (w & 1) * 64;
  const int lr = lane & 15, lk = lane >> 4;
  const int srow = tid >> 1, sc0 = (tid & 1) * 16;

  const _Float16* ga = Qp + ((size_t)(tm * BM + srow) * HEADS + h) * DH + sc0;
  const _Float16* gb = Kp + ((size_t)(tn * BN + srow) * HEADS + h) * DH + sc0;

  f32x4 acc[4][4] = {};
  gemm_f16_core<DH / BK>(ga, gb, As, Bs, srow, sc0, wr, wc, lr, lk, acc);

#pragma unroll
  for (int i = 0; i < 4; ++i)
#pragma unroll
    for (int j = 0; j < 4; ++j) {
      const int m = tn * BN + wc + j * 16 + lr;
#pragma unroll
      for (int q = 0; q < 4; ++q) {
        const int n = tm * BM + wr + i * 16 + lk * 4 + q;
        S[((size_t)h * BATCH + n) * BATCH + m] = 32.0f * acc[i][j][q];
      }
    }
}

// row-softmax over m (512), one wave per (h,n) row; fp32 in, fp16 out
__global__ __launch_bounds__(64) void softmax_kernel(
    const float* __restrict__ S, _Float16* __restrict__ A) {
  const size_t r = (size_t)blockIdx.x * BATCH;
  const int l = threadIdx.x;
  float v[8];
  float mx = -1e30f;
#pragma unroll
  for (int i = 0; i < 8; ++i) { v[i] = S[r + i * 64 + l]; mx = fmaxf(mx, v[i]); }
#pragma unroll
  for (int off = 32; off; off >>= 1) mx = fmaxf(mx, __shfl_xor(mx, off));
  float sum = 0.f;
#pragma unroll
  for (int i = 0; i < 8; ++i) { v[i] = __expf(v[i] - mx); sum += v[i]; }
#pragma unroll
  for (int off = 32; off; off >>= 1) sum += __shfl_xor(sum, off);
  const float inv = 1.f / sum;
#pragma unroll
  for (int i = 0; i < 8; ++i) A[r + i * 64 + l] = (_Float16)(v[i] * inv);
}

// Out[n,h,e] = sum_m At[h,n,m] * VpT[h,e,m]   (fp32 out)
__global__ __launch_bounds__(256, 4) void pv_kernel(
    const _Float16* __restrict__ At, const _Float16* __restrict__ VpT,
    float* __restrict__ Out) {
  __shared__ _Float16 As[2][BM * LDW];
  __shared__ _Float16 Bs[2][BN * LDW];
  const int tid = threadIdx.x;
  const int l  = xcd_swz(blockIdx.x, 256);
  const int h  = l >> 5, bx = l & 31;
  const int tm = bx & 3, tn = bx >> 2;
  const int lane = tid & 63, w = tid >> 6;
  const int wr = (w >> 1) * 64, wc = (w & 1) * 64;
  const int lr = lane & 15, lk = lane >> 4;
  const int srow = tid >> 1, sc0 = (tid & 1) * 16;

  const _Float16* ga = At  + ((size_t)h * BATCH + tm * BM + srow) * BATCH + sc0;
  const _Float16* gb = VpT + ((size_t)h * DH   + tn * BN + srow) * BATCH + sc0;

  f32x4 acc[4][4] = {};
  gemm_f16_core<BATCH / BK>(ga, gb, As, Bs, srow, sc0, wr, wc, lr, lk, acc);

#pragma unroll
  for (int i = 0; i < 4; ++i)
#pragma unroll
    for (int j = 0; j < 4; ++j) {
      const int e = tn * BN + wc + j * 16 + lr;
#pragma unroll
      for (int q = 0; q < 4; ++q) {
        const int n = tm * BM + wr + i * 16 + lk * 4 + q;
        Out[((size_t)n * HEADS + h) * DH + e] = acc[i][j][q];
      }
    }
}

}  // namespace

extern "C" void kernel_launch(void* const* d_in, const int* in_sizes, int n_in,
                              void* d_out, int out_size, void* d_ws, size_t ws_size,
                              hipStream_t stream) {
  (void)in_sizes; (void)n_in; (void)out_size; (void)ws_size;
  const float* q  = (const float*)d_in[0];
  const float* k  = (const float*)d_in[1];
  const float* v  = (const float*)d_in[2];
  const float* W1 = (const float*)d_in[3];
  const float* b1 = (const float*)d_in[4];
  const float* W2 = (const float*)d_in[5];
  const float* b2 = (const float*)d_in[6];
  const float* W3 = (const float*)d_in[7];
  const float* b3 = (const float*)d_in[8];
  float* out = (float*)d_out;

  // workspace layout (36 MB total)
  _Float16* Qp  = (_Float16*)d_ws;                       // 8 MB
  _Float16* Kp  = Qp + (size_t)BATCH * HEADS * DH;       // 8 MB
  _Float16* VpT = Kp + (size_t)BATCH * HEADS * DH;       // 8 MB ([h][e][m])
  float*    S   = (float*)(VpT + (size_t)BATCH * HEADS * DH);      // 8 MB
  _Float16* At  = (_Float16*)(S + (size_t)HEADS * BATCH * BATCH);  // 4 MB

  const dim3 blk(256);
  proj_kernel<<<dim3(768), blk, 0, stream>>>(q, k, v, W1, b1, W2, b2, W3, b3, Qp, Kp, VpT);
  score_kernel<<<dim3(128), blk, 0, stream>>>(Qp, Kp, S);
  softmax_kernel<<<dim3(HEADS * BATCH), dim3(64), 0, stream>>>(S, At);
  pv_kernel<<<dim3(256), blk, 0, stream>>>(At, VpT, out);
}

// Round 5
// 108.240 us; speedup vs baseline: 13.7690x; 4.0167x over previous
//
#include <hip/hip_runtime.h>

typedef _Float16 half8 __attribute__((ext_vector_type(8)));
typedef float f32x4 __attribute__((ext_vector_type(4)));

namespace {

constexpr int HEADS = 8;
constexpr int BATCH = 512;
constexpr int DH    = 1024;          // per-head dim
constexpr int CHW   = HEADS * DH;    // 8192

constexpr int BM = 128, BN = 128, BK = 32;
constexpr int LDW = BK + 8;          // padded LDS stride (halves): 40

// dispatch-index d runs on XCD d%8; give each XCD a contiguous logical chunk
__device__ __forceinline__ int xcd_swz(int bid, int nwg) {
  const int q = nwg >> 3;  // all our grids are %8 == 0
  return (bid & 7) * q + (bid >> 3);
}

// static-only f32x8 -> f16x8 conversion (no memory arrays -> no SROA hazard)
__device__ __forceinline__ half8 cvt8(float4 a, float4 b) {
  half8 r;
  r[0] = (_Float16)a.x; r[1] = (_Float16)a.y; r[2] = (_Float16)a.z; r[3] = (_Float16)a.w;
  r[4] = (_Float16)b.x; r[5] = (_Float16)b.y; r[6] = (_Float16)b.z; r[7] = (_Float16)b.w;
  return r;
}

// Fused Q/K/V projection. z selects (X, W, bias, dst).
// Q/K written [h][n][e]; V written transposed [h][e][n].
// dbuf LDS, ONE barrier per K-step, 1-ahead float4 register prefetch (all named regs).
__global__ __launch_bounds__(256) void proj_kernel(
    const float* __restrict__ Xq, const float* __restrict__ Xk, const float* __restrict__ Xv,
    const float* __restrict__ W1, const float* __restrict__ b1,
    const float* __restrict__ W2, const float* __restrict__ b2,
    const float* __restrict__ W3, const float* __restrict__ b3,
    _Float16* __restrict__ Qp, _Float16* __restrict__ Kp, _Float16* __restrict__ VpT) {
  __shared__ _Float16 As[2][BM * LDW];
  __shared__ _Float16 Bs[2][BN * LDW];
  const int tid = threadIdx.x;
  const int l  = xcd_swz(blockIdx.x, 768);
  const int z  = l >> 8, rem = l & 255;
  const int h  = rem >> 5, bx = rem & 31;
  const int tm = bx & 3, tn = bx >> 2;
  const float* X    = (z == 0) ? Xq : (z == 1) ? Xk : Xv;
  const float* W    = (z == 0) ? W1 : (z == 1) ? W2 : W3;
  const float* bias = (z == 0) ? b1 : (z == 1) ? b2 : b3;
  _Float16*    P    = (z == 0) ? Qp : (z == 1) ? Kp : VpT;

  const int lane = tid & 63, w = tid >> 6;
  const int wr = (w >> 1) * 64, wc = (w & 1) * 64;
  const int lr = lane & 15, lk = lane >> 4;
  const int srow = tid >> 1, sc0 = (tid & 1) * 16;

  const float* ga = X + (size_t)(tm * BM + srow) * CHW + (size_t)h * DH + sc0;
  const float* gb = W + (size_t)h * DH * DH + (size_t)(tn * BN + srow) * DH + sc0;

  constexpr int NT = DH / BK;  // 32
  float4 ra0, ra1, ra2, ra3, rb0, rb1, rb2, rb3;
  // prologue: tile0 -> regs -> cvt -> buf0; tile1 -> regs
  ra0 = ((const float4*)ga)[0]; ra1 = ((const float4*)ga)[1];
  ra2 = ((const float4*)ga)[2]; ra3 = ((const float4*)ga)[3];
  rb0 = ((const float4*)gb)[0]; rb1 = ((const float4*)gb)[1];
  rb2 = ((const float4*)gb)[2]; rb3 = ((const float4*)gb)[3];
  ga += BK; gb += BK;
  *(half8*)&As[0][srow * LDW + sc0]     = cvt8(ra0, ra1);
  *(half8*)&As[0][srow * LDW + sc0 + 8] = cvt8(ra2, ra3);
  *(half8*)&Bs[0][srow * LDW + sc0]     = cvt8(rb0, rb1);
  *(half8*)&Bs[0][srow * LDW + sc0 + 8] = cvt8(rb2, rb3);
  ra0 = ((const float4*)ga)[0]; ra1 = ((const float4*)ga)[1];
  ra2 = ((const float4*)ga)[2]; ra3 = ((const float4*)ga)[3];
  rb0 = ((const float4*)gb)[0]; rb1 = ((const float4*)gb)[1];
  rb2 = ((const float4*)gb)[2]; rb3 = ((const float4*)gb)[3];
  ga += BK; gb += BK;
  __syncthreads();

  f32x4 acc[4][4] = {};
  int c = 0;
#pragma unroll 1
  for (int t = 0; t < NT; ++t) {
    const _Float16* Ac = As[c];
    const _Float16* Bc = Bs[c];
    half8 av[4], bv[4];
#pragma unroll
    for (int i = 0; i < 4; ++i)
      av[i] = *(const half8*)&Ac[(wr + i * 16 + lr) * LDW + lk * 8];
#pragma unroll
    for (int j = 0; j < 4; ++j)
      bv[j] = *(const half8*)&Bc[(wc + j * 16 + lr) * LDW + lk * 8];
    if (t + 1 < NT) {  // stage tile t+1 (in regs) into other buffer
      _Float16* An = As[c ^ 1];
      _Float16* Bn = Bs[c ^ 1];
      *(half8*)&An[srow * LDW + sc0]     = cvt8(ra0, ra1);
      *(half8*)&An[srow * LDW + sc0 + 8] = cvt8(ra2, ra3);
      *(half8*)&Bn[srow * LDW + sc0]     = cvt8(rb0, rb1);
      *(half8*)&Bn[srow * LDW + sc0 + 8] = cvt8(rb2, rb3);
      if (t + 2 < NT) {  // prefetch tile t+2 into the (consumed) named regs
        ra0 = ((const float4*)ga)[0]; ra1 = ((const float4*)ga)[1];
        ra2 = ((const float4*)ga)[2]; ra3 = ((const float4*)ga)[3];
        rb0 = ((const float4*)gb)[0]; rb1 = ((const float4*)gb)[1];
        rb2 = ((const float4*)gb)[2]; rb3 = ((const float4*)gb)[3];
        ga += BK; gb += BK;
      }
    }
#pragma unroll
    for (int i = 0; i < 4; ++i)
#pragma unroll
      for (int j = 0; j < 4; ++j)
        acc[i][j] = __builtin_amdgcn_mfma_f32_16x16x32_f16(av[i], bv[j], acc[i][j], 0, 0, 0);
    __syncthreads();
    c ^= 1;
  }

#pragma unroll
  for (int i = 0; i < 4; ++i)
#pragma unroll
    for (int j = 0; j < 4; ++j) {
      const int e = tn * BN + wc + j * 16 + lr;
      const float bb = bias[h * DH + e];
#pragma unroll
      for (int q = 0; q < 4; ++q) {
        const int n = tm * BM + wr + i * 16 + lk * 4 + q;
        const float val = acc[i][j][q] + bb;
        if (z != 2) P[((size_t)h * BATCH + n) * DH + e] = (_Float16)val;
        else        P[((size_t)h * DH + e) * BATCH + n] = (_Float16)val;
      }
    }
}

// f16 NT-GEMM body: dbuf LDS, one barrier/iter, single STATIC prefetch slot.
template <int NT>
__device__ __forceinline__ void gemm_f16_core(
    const _Float16* ga, const _Float16* gb,
    _Float16 (*As)[BM * LDW], _Float16 (*Bs)[BN * LDW],
    int srow, int sc0, int wr, int wc, int lr, int lk, f32x4 (&acc)[4][4]) {
  half8 rA0 = ((const half8*)ga)[0], rA1 = ((const half8*)ga)[1];
  half8 rB0 = ((const half8*)gb)[0], rB1 = ((const half8*)gb)[1];
  ga += BK; gb += BK;
  *(half8*)&As[0][srow * LDW + sc0]     = rA0;
  *(half8*)&As[0][srow * LDW + sc0 + 8] = rA1;
  *(half8*)&Bs[0][srow * LDW + sc0]     = rB0;
  *(half8*)&Bs[0][srow * LDW + sc0 + 8] = rB1;
  rA0 = ((const half8*)ga)[0]; rA1 = ((const half8*)ga)[1];
  rB0 = ((const half8*)gb)[0]; rB1 = ((const half8*)gb)[1];
  ga += BK; gb += BK;
  __syncthreads();

  int c = 0;
#pragma unroll 1
  for (int t = 0; t < NT; ++t) {
    const _Float16* Ac = As[c];
    const _Float16* Bc = Bs[c];
    half8 av[4], bv[4];
#pragma unroll
    for (int i = 0; i < 4; ++i)
      av[i] = *(const half8*)&Ac[(wr + i * 16 + lr) * LDW + lk * 8];
#pragma unroll
    for (int j = 0; j < 4; ++j)
      bv[j] = *(const half8*)&Bc[(wc + j * 16 + lr) * LDW + lk * 8];
    if (t + 1 < NT) {
      _Float16* An = As[c ^ 1];
      _Float16* Bn = Bs[c ^ 1];
      *(half8*)&An[srow * LDW + sc0]     = rA0;
      *(half8*)&An[srow * LDW + sc0 + 8] = rA1;
      *(half8*)&Bn[srow * LDW + sc0]     = rB0;
      *(half8*)&Bn[srow * LDW + sc0 + 8] = rB1;
      if (t + 2 < NT) {
        rA0 = ((const half8*)ga)[0]; rA1 = ((const half8*)ga)[1];
        rB0 = ((const half8*)gb)[0]; rB1 = ((const half8*)gb)[1];
        ga += BK; gb += BK;
      }
    }
#pragma unroll
    for (int i = 0; i < 4; ++i)
#pragma unroll
      for (int j = 0; j < 4; ++j)
        acc[i][j] = __builtin_amdgcn_mfma_f32_16x16x32_f16(av[i], bv[j], acc[i][j], 0, 0, 0);
    __syncthreads();
    c ^= 1;
  }
}

// S[h,n,m] = 32 * sum_e Qp[h,n,e] * Kp[h,m,e]   (fp32 out)
__global__ __launch_bounds__(256) void score_kernel(
    const _Float16* __restrict__ Qp, const _Float16* __restrict__ Kp,
    float* __restrict__ S) {
  __shared__ _Float16 As[2][BM * LDW];
  __shared__ _Float16 Bs[2][BN * LDW];
  const int tid = threadIdx.x;
  const int l  = xcd_swz(blockIdx.x, 128);
  const int h  = l >> 4, bx = l & 15;
  const int tm = bx & 3, tn = bx >> 2;
  const int lane = tid & 63, w = tid >> 6;
  const int wr = (w >> 1) * 64, wc = (w & 1) * 64;
  const int lr = lane & 15, lk = lane >> 4;
  const int srow = tid >> 1, sc0 = (tid & 1) * 16;

  const _Float16* ga = Qp + ((size_t)h * BATCH + tm * BM + srow) * DH + sc0;
  const _Float16* gb = Kp + ((size_t)h * BATCH + tn * BN + srow) * DH + sc0;

  f32x4 acc[4][4] = {};
  gemm_f16_core<DH / BK>(ga, gb, As, Bs, srow, sc0, wr, wc, lr, lk, acc);

#pragma unroll
  for (int i = 0; i < 4; ++i)
#pragma unroll
    for (int j = 0; j < 4; ++j) {
      const int m = tn * BN + wc + j * 16 + lr;
#pragma unroll
      for (int q = 0; q < 4; ++q) {
        const int n = tm * BM + wr + i * 16 + lk * 4 + q;
        S[((size_t)h * BATCH + n) * BATCH + m] = 32.0f * acc[i][j][q];
      }
    }
}

// row-softmax over m (512), one wave per (h,n) row; fp32 in, fp16 out
__global__ __launch_bounds__(64) void softmax_kernel(
    const float* __restrict__ S, _Float16* __restrict__ A) {
  const size_t r = (size_t)blockIdx.x * BATCH;
  const int l = threadIdx.x;
  float v[8];
  float mx = -1e30f;
#pragma unroll
  for (int i = 0; i < 8; ++i) { v[i] = S[r + i * 64 + l]; mx = fmaxf(mx, v[i]); }
#pragma unroll
  for (int off = 32; off; off >>= 1) mx = fmaxf(mx, __shfl_xor(mx, off));
  float sum = 0.f;
#pragma unroll
  for (int i = 0; i < 8; ++i) { v[i] = __expf(v[i] - mx); sum += v[i]; }
#pragma unroll
  for (int off = 32; off; off >>= 1) sum += __shfl_xor(sum, off);
  const float inv = 1.f / sum;
#pragma unroll
  for (int i = 0; i < 8; ++i) A[r + i * 64 + l] = (_Float16)(v[i] * inv);
}

// Out[n,h,e] = sum_m At[h,n,m] * VpT[h,e,m]   (fp32 out)
__global__ __launch_bounds__(256) void pv_kernel(
    const _Float16* __restrict__ At, const _Float16* __restrict__ VpT,
    float* __restrict__ Out) {
  __shared__ _Float16 As[2][BM * LDW];
  __shared__ _Float16 Bs[2][BN * LDW];
  const int tid = threadIdx.x;
  const int l  = xcd_swz(blockIdx.x, 256);
  const int h  = l >> 5, bx = l & 31;
  const int tm = bx & 3, tn = bx >> 2;
  const int lane = tid & 63, w = tid >> 6;
  const int wr = (w >> 1) * 64, wc = (w & 1) * 64;
  const int lr = lane & 15, lk = lane >> 4;
  const int srow = tid >> 1, sc0 = (tid & 1) * 16;

  const _Float16* ga = At  + ((size_t)h * BATCH + tm * BM + srow) * BATCH + sc0;
  const _Float16* gb = VpT + ((size_t)h * DH   + tn * BN + srow) * BATCH + sc0;

  f32x4 acc[4][4] = {};
  gemm_f16_core<BATCH / BK>(ga, gb, As, Bs, srow, sc0, wr, wc, lr, lk, acc);

#pragma unroll
  for (int i = 0; i < 4; ++i)
#pragma unroll
    for (int j = 0; j < 4; ++j) {
      const int e = tn * BN + wc + j * 16 + lr;
#pragma unroll
      for (int q = 0; q < 4; ++q) {
        const int n = tm * BM + wr + i * 16 + lk * 4 + q;
        Out[((size_t)n * HEADS + h) * DH + e] = acc[i][j][q];
      }
    }
}

}  // namespace

extern "C" void kernel_launch(void* const* d_in, const int* in_sizes, int n_in,
                              void* d_out, int out_size, void* d_ws, size_t ws_size,
                              hipStream_t stream) {
  (void)in_sizes; (void)n_in; (void)out_size; (void)ws_size;
  const float* q  = (const float*)d_in[0];
  const float* k  = (const float*)d_in[1];
  const float* v  = (const float*)d_in[2];
  const float* W1 = (const float*)d_in[3];
  const float* b1 = (const float*)d_in[4];
  const float* W2 = (const float*)d_in[5];
  const float* b2 = (const float*)d_in[6];
  const float* W3 = (const float*)d_in[7];
  const float* b3 = (const float*)d_in[8];
  float* out = (float*)d_out;

  // workspace layout (36 MB total)
  _Float16* Qp  = (_Float16*)d_ws;                       // [h][n][e] 8 MB
  _Float16* Kp  = Qp + (size_t)BATCH * HEADS * DH;       // [h][m][e] 8 MB
  _Float16* VpT = Kp + (size_t)BATCH * HEADS * DH;       // [h][e][m] 8 MB
  float*    S   = (float*)(VpT + (size_t)BATCH * HEADS * DH);      // 8 MB
  _Float16* At  = (_Float16*)(S + (size_t)HEADS * BATCH * BATCH);  // 4 MB

  const dim3 blk(256);
  proj_kernel<<<dim3(768), blk, 0, stream>>>(q, k, v, W1, b1, W2, b2, W3, b3, Qp, Kp, VpT);
  score_kernel<<<dim3(128), blk, 0, stream>>>(Qp, Kp, S);
  softmax_kernel<<<dim3(HEADS * BATCH), dim3(64), 0, stream>>>(S, At);
  pv_kernel<<<dim3(256), blk, 0, stream>>>(At, VpT, out);
}